// Round 3
// baseline (167.045 us; speedup 1.0000x reference)
//
#include <hip/hip_runtime.h>
#include <math.h>

typedef unsigned short u16;
typedef __bf16 bf16x8 __attribute__((ext_vector_type(8)));
typedef float f32x4 __attribute__((ext_vector_type(4)));

// ---------- helpers ----------
__device__ inline u16 bf16_rn(float x) {
    unsigned u = __float_as_uint(x);
    return (u16)((u + 0x7FFFu + ((u >> 16) & 1u)) >> 16);
}
__device__ inline void split2(float x, u16& h, u16& l) {
    h = bf16_rn(x);
    float hf = __uint_as_float(((unsigned)h) << 16);
    l = bf16_rn(x - hf);
}
__device__ inline uint2 pack4(u16 a, u16 b, u16 c, u16 d) {
    uint2 r;
    r.x = (unsigned)a | ((unsigned)b << 16);
    r.y = (unsigned)c | ((unsigned)d << 16);
    return r;
}
__device__ inline f32x4 mfma16(bf16x8 a, bf16x8 b, f32x4 c) {
    return __builtin_amdgcn_mfma_f32_16x16x32_bf16(a, b, c, 0, 0, 0);
}

// ---------- fused init: blocks 0..1023 split W1 x-rows -> Ah/Al; blocks 1024..1035 build Z + zero ----------
__global__ __launch_bounds__(256) void k_init_prep(const float* __restrict__ x,
                                                   const float* __restrict__ q,
                                                   const float* __restrict__ p,
                                                   const float* __restrict__ W1,
                                                   float* __restrict__ Z,
                                                   float* __restrict__ out,
                                                   float* __restrict__ uv,
                                                   u16* __restrict__ Ah, u16* __restrict__ Al) {
    int b = blockIdx.x;
    if (b < 1024) {
        int idx = (b * 256 + threadIdx.x) * 4;  // 1M floats = W1 rows 0..1023
        float4 v = *(const float4*)(W1 + idx);
        u16 h0, l0, h1, l1, h2, l2, h3, l3;
        split2(v.x, h0, l0); split2(v.y, h1, l1); split2(v.z, h2, l2); split2(v.w, h3, l3);
        *(uint2*)&Ah[idx] = pack4(h0, h1, h2, h3);
        *(uint2*)&Al[idx] = pack4(l0, l1, l2, l3);
    } else {
        int j = (b - 1024) * 256 + threadIdx.x;  // 0..3071
        if (j < 2048) { out[j] = 0.f; uv[j] = 0.f; }
        Z[j] = (j < 1024) ? x[j] : (j < 2048 ? q[j - 1024] : p[j - 2048]);
    }
}

__global__ __launch_bounds__(256) void k_u_partial(const float* __restrict__ W1,
                                                   const float* __restrict__ Z,
                                                   float* __restrict__ Uacc) {
    int k = blockIdx.x * 256 + threadIdx.x;  // grid (4,48)
    int j0 = blockIdx.y * 64;
    __shared__ float zs[64];
    if (threadIdx.x < 64) zs[threadIdx.x] = Z[j0 + threadIdx.x];
    __syncthreads();
    float acc = 0.f;
#pragma unroll 8
    for (int j = 0; j < 64; ++j) acc += zs[j] * W1[(j0 + j) * 1024 + k];
    atomicAdd(&Uacc[k], acc);
}

__global__ __launch_bounds__(256) void k_h1(const float* __restrict__ Uacc,
                                            const float* __restrict__ b1,
                                            float* __restrict__ H1, float* __restrict__ D1) {
    int k = blockIdx.x * 256 + threadIdx.x;  // grid 4
    float h = tanhf(Uacc[k] + b1[k]);
    H1[k] = h;
    D1[k] = 1.f - h * h;
}

// ---------- fused W2 pass: split W2 -> W2h/W2l, transpose+d1-scale -> WTh/WTl, and Vacc partials ----------
__global__ __launch_bounds__(256) void k_w2v(const float* __restrict__ W2,
                                             const float* __restrict__ D1,
                                             const float* __restrict__ H1,
                                             u16* __restrict__ W2h, u16* __restrict__ W2l,
                                             u16* __restrict__ WTh, u16* __restrict__ WTl,
                                             float* __restrict__ Vacc) {
    __shared__ float T[64][65];
    int k0 = blockIdx.y * 64, m0 = blockIdx.x * 64;
    int t = threadIdx.x;
    int rr = t >> 4, cc = (t & 15) * 4;
    float4 vp = make_float4(0.f, 0.f, 0.f, 0.f);
#pragma unroll
    for (int j = 0; j < 4; ++j) {
        int r = rr + j * 16;
        float4 v = *(const float4*)(W2 + (k0 + r) * 1024 + m0 + cc);
        T[r][cc + 0] = v.x; T[r][cc + 1] = v.y; T[r][cc + 2] = v.z; T[r][cc + 3] = v.w;
        u16 h0, l0, h1, l1, h2, l2, h3, l3;
        split2(v.x, h0, l0); split2(v.y, h1, l1); split2(v.z, h2, l2); split2(v.w, h3, l3);
        *(uint2*)&W2h[(k0 + r) * 1024 + m0 + cc] = pack4(h0, h1, h2, h3);
        *(uint2*)&W2l[(k0 + r) * 1024 + m0 + cc] = pack4(l0, l1, l2, l3);
        float hk = H1[k0 + r];
        vp.x += hk * v.x; vp.y += hk * v.y; vp.z += hk * v.z; vp.w += hk * v.w;
    }
    // reduce Vacc partial across the 4 lanes sharing (lane&15) within the wave
    vp.x += __shfl_xor(vp.x, 16); vp.y += __shfl_xor(vp.y, 16);
    vp.z += __shfl_xor(vp.z, 16); vp.w += __shfl_xor(vp.w, 16);
    vp.x += __shfl_xor(vp.x, 32); vp.y += __shfl_xor(vp.y, 32);
    vp.z += __shfl_xor(vp.z, 32); vp.w += __shfl_xor(vp.w, 32);
    if (((t & 63) >> 4) == 0) {
        atomicAdd(&Vacc[m0 + cc + 0], vp.x);
        atomicAdd(&Vacc[m0 + cc + 1], vp.y);
        atomicAdd(&Vacc[m0 + cc + 2], vp.z);
        atomicAdd(&Vacc[m0 + cc + 3], vp.w);
    }
    __syncthreads();
#pragma unroll
    for (int j = 0; j < 4; ++j) {
        int mrow = rr + j * 16;
        float f0 = T[cc + 0][mrow] * D1[k0 + cc + 0];
        float f1 = T[cc + 1][mrow] * D1[k0 + cc + 1];
        float f2 = T[cc + 2][mrow] * D1[k0 + cc + 2];
        float f3 = T[cc + 3][mrow] * D1[k0 + cc + 3];
        u16 h0, l0, h1, l1, h2, l2, h3, l3;
        split2(f0, h0, l0); split2(f1, h1, l1); split2(f2, h2, l2); split2(f3, h3, l3);
        *(uint2*)&WTh[(m0 + mrow) * 1024 + k0 + cc] = pack4(h0, h1, h2, h3);
        *(uint2*)&WTl[(m0 + mrow) * 1024 + k0 + cc] = pack4(l0, l1, l2, l3);
    }
}

__global__ __launch_bounds__(256) void k_h2(const float* __restrict__ Vacc,
                                            const float* __restrict__ b2,
                                            const float* __restrict__ W3,
                                            float* __restrict__ Svec, float* __restrict__ Cvec) {
    int m = blockIdx.x * 256 + threadIdx.x;  // grid 4
    float h = tanhf(Vacc[m] + b2[m]);
    float d2 = 1.f - h * h;
    float w3 = W3[m];
    Svec[m] = d2 * w3;
    Cvec[m] = -2.f * h * d2 * w3;
}

__global__ __launch_bounds__(256) void k_g(const float* __restrict__ W2,
                                           const float* __restrict__ Svec,
                                           const float* __restrict__ H1,
                                           const float* __restrict__ D1,
                                           float* __restrict__ Avec) {
    int k = blockIdx.x;  // grid 1024
    int t = threadIdx.x;
    float acc = 0.f;
#pragma unroll
    for (int m = t; m < 1024; m += 256) acc += W2[k * 1024 + m] * Svec[m];
    for (int o = 32; o; o >>= 1) acc += __shfl_down(acc, o);
    __shared__ float red[4];
    int lane = t & 63, w = t >> 6;
    if (lane == 0) red[w] = acc;
    __syncthreads();
    if (t == 0) Avec[k] = -2.f * H1[k] * D1[k] * (red[0] + red[1] + red[2] + red[3]);
}

// ---------- register-streaming MFMA GEMMs (no LDS, software prefetch) ----------
// S[i,m] = Cvec[m] * sum_k Ah/Al[i,k] * WT[m,k]   (WT pre-scaled by d1)
__global__ __launch_bounds__(256) void k_gemm1(const u16* __restrict__ Ah, const u16* __restrict__ Al,
                                               const u16* __restrict__ Bh, const u16* __restrict__ Bl,
                                               const float* __restrict__ Cvec,
                                               u16* __restrict__ Sh, u16* __restrict__ Sl) {
    int tid = threadIdx.x, lane = tid & 63, wv = tid >> 6;
    int wy = wv >> 1, wx = wv & 1;
    int i0 = blockIdx.y * 64, m0 = blockIdx.x * 64;
    int tx = lane & 15, qy = lane >> 4;
    int off = qy * 8;
    const u16* a0h = Ah + (i0 + wy * 32 + tx) * 1024 + off;
    const u16* a1h = a0h + 16 * 1024;
    const u16* a0l = Al + (i0 + wy * 32 + tx) * 1024 + off;
    const u16* a1l = a0l + 16 * 1024;
    const u16* b0h = Bh + (m0 + wx * 32 + tx) * 1024 + off;
    const u16* b1h = b0h + 16 * 1024;
    const u16* b0l = Bl + (m0 + wx * 32 + tx) * 1024 + off;
    const u16* b1l = b0l + 16 * 1024;
    f32x4 acc[2][2];
#pragma unroll
    for (int a = 0; a < 2; ++a)
#pragma unroll
        for (int b = 0; b < 2; ++b) acc[a][b] = (f32x4){0.f, 0.f, 0.f, 0.f};

    bf16x8 cA0h = *(const bf16x8*)a0h, cA1h = *(const bf16x8*)a1h;
    bf16x8 cA0l = *(const bf16x8*)a0l, cA1l = *(const bf16x8*)a1l;
    bf16x8 cB0h = *(const bf16x8*)b0h, cB1h = *(const bf16x8*)b1h;
    bf16x8 cB0l = *(const bf16x8*)b0l, cB1l = *(const bf16x8*)b1l;

#pragma unroll 2
    for (int k0 = 0; k0 < 1024; k0 += 32) {
        int kn = (k0 + 32) & 1023;  // last iter wraps to 0 (discarded), avoids branch
        bf16x8 nA0h = *(const bf16x8*)(a0h + kn), nA1h = *(const bf16x8*)(a1h + kn);
        bf16x8 nA0l = *(const bf16x8*)(a0l + kn), nA1l = *(const bf16x8*)(a1l + kn);
        bf16x8 nB0h = *(const bf16x8*)(b0h + kn), nB1h = *(const bf16x8*)(b1h + kn);
        bf16x8 nB0l = *(const bf16x8*)(b0l + kn), nB1l = *(const bf16x8*)(b1l + kn);
        acc[0][0] = mfma16(cA0h, cB0h, acc[0][0]);
        acc[0][0] = mfma16(cA0h, cB0l, acc[0][0]);
        acc[0][0] = mfma16(cA0l, cB0h, acc[0][0]);
        acc[0][1] = mfma16(cA0h, cB1h, acc[0][1]);
        acc[0][1] = mfma16(cA0h, cB1l, acc[0][1]);
        acc[0][1] = mfma16(cA0l, cB1h, acc[0][1]);
        acc[1][0] = mfma16(cA1h, cB0h, acc[1][0]);
        acc[1][0] = mfma16(cA1h, cB0l, acc[1][0]);
        acc[1][0] = mfma16(cA1l, cB0h, acc[1][0]);
        acc[1][1] = mfma16(cA1h, cB1h, acc[1][1]);
        acc[1][1] = mfma16(cA1h, cB1l, acc[1][1]);
        acc[1][1] = mfma16(cA1l, cB1h, acc[1][1]);
        cA0h = nA0h; cA1h = nA1h; cA0l = nA0l; cA1l = nA1l;
        cB0h = nB0h; cB1h = nB1h; cB0l = nB0l; cB1l = nB1l;
    }
#pragma unroll
    for (int sj = 0; sj < 2; ++sj) {
        int m = m0 + wx * 32 + sj * 16 + tx;
        float cm = Cvec[m];
#pragma unroll
        for (int si = 0; si < 2; ++si) {
            int ib = i0 + wy * 32 + si * 16 + qy * 4;
#pragma unroll
            for (int r = 0; r < 4; ++r) {
                float v = acc[si][sj][r] * cm;
                u16 h, l;
                split2(v, h, l);
                Sh[(ib + r) * 1024 + m] = h;
                Sl[(ib + r) * 1024 + m] = l;
            }
        }
    }
}

// Wm[i,k] = sum_m S[i,m]*W2[k,m]; fused epilogue -> out
__global__ __launch_bounds__(256) void k_gemm2(const u16* __restrict__ Sh, const u16* __restrict__ Sl,
                                               const u16* __restrict__ W2h, const u16* __restrict__ W2l,
                                               const float* __restrict__ W1,
                                               const float* __restrict__ D1,
                                               const float* __restrict__ Avec,
                                               float* __restrict__ out) {
    int tid = threadIdx.x, lane = tid & 63, wv = tid >> 6;
    int wy = wv >> 1, wx = wv & 1;
    int i0 = blockIdx.y * 64, k0g = blockIdx.x * 64;
    int tx = lane & 15, qy = lane >> 4;
    int off = qy * 8;
    const u16* a0h = Sh + (i0 + wy * 32 + tx) * 1024 + off;
    const u16* a1h = a0h + 16 * 1024;
    const u16* a0l = Sl + (i0 + wy * 32 + tx) * 1024 + off;
    const u16* a1l = a0l + 16 * 1024;
    const u16* b0h = W2h + (k0g + wx * 32 + tx) * 1024 + off;
    const u16* b1h = b0h + 16 * 1024;
    const u16* b0l = W2l + (k0g + wx * 32 + tx) * 1024 + off;
    const u16* b1l = b0l + 16 * 1024;
    f32x4 acc[2][2];
#pragma unroll
    for (int a = 0; a < 2; ++a)
#pragma unroll
        for (int b = 0; b < 2; ++b) acc[a][b] = (f32x4){0.f, 0.f, 0.f, 0.f};

    bf16x8 cA0h = *(const bf16x8*)a0h, cA1h = *(const bf16x8*)a1h;
    bf16x8 cA0l = *(const bf16x8*)a0l, cA1l = *(const bf16x8*)a1l;
    bf16x8 cB0h = *(const bf16x8*)b0h, cB1h = *(const bf16x8*)b1h;
    bf16x8 cB0l = *(const bf16x8*)b0l, cB1l = *(const bf16x8*)b1l;

#pragma unroll 2
    for (int m0 = 0; m0 < 1024; m0 += 32) {
        int mn = (m0 + 32) & 1023;
        bf16x8 nA0h = *(const bf16x8*)(a0h + mn), nA1h = *(const bf16x8*)(a1h + mn);
        bf16x8 nA0l = *(const bf16x8*)(a0l + mn), nA1l = *(const bf16x8*)(a1l + mn);
        bf16x8 nB0h = *(const bf16x8*)(b0h + mn), nB1h = *(const bf16x8*)(b1h + mn);
        bf16x8 nB0l = *(const bf16x8*)(b0l + mn), nB1l = *(const bf16x8*)(b1l + mn);
        acc[0][0] = mfma16(cA0h, cB0h, acc[0][0]);
        acc[0][0] = mfma16(cA0h, cB0l, acc[0][0]);
        acc[0][0] = mfma16(cA0l, cB0h, acc[0][0]);
        acc[0][1] = mfma16(cA0h, cB1h, acc[0][1]);
        acc[0][1] = mfma16(cA0h, cB1l, acc[0][1]);
        acc[0][1] = mfma16(cA0l, cB1h, acc[0][1]);
        acc[1][0] = mfma16(cA1h, cB0h, acc[1][0]);
        acc[1][0] = mfma16(cA1h, cB0l, acc[1][0]);
        acc[1][0] = mfma16(cA1l, cB0h, acc[1][0]);
        acc[1][1] = mfma16(cA1h, cB1h, acc[1][1]);
        acc[1][1] = mfma16(cA1h, cB1l, acc[1][1]);
        acc[1][1] = mfma16(cA1l, cB1h, acc[1][1]);
        cA0h = nA0h; cA1h = nA1h; cA0l = nA0l; cA1l = nA1l;
        cB0h = nB0h; cB1h = nB1h; cB0l = nB0l; cB1l = nB1l;
    }
    // fused epilogue: DR = Avec[k]*W1[i,k] + D1[k]*Wm[i,k]; dot with q/p rows of W1
    int kk[2];
    float d1v[2], avv[2];
#pragma unroll
    for (int sj = 0; sj < 2; ++sj) {
        kk[sj] = k0g + wx * 32 + sj * 16 + tx;
        d1v[sj] = D1[kk[sj]];
        avv[sj] = Avec[kk[sj]];
    }
#pragma unroll
    for (int si = 0; si < 2; ++si) {
        int ib = i0 + wy * 32 + si * 16 + qy * 4;
#pragma unroll
        for (int r = 0; r < 4; ++r) {
            int i = ib + r;
            float pq = 0.f, pp = 0.f;
#pragma unroll
            for (int sj = 0; sj < 2; ++sj) {
                int k = kk[sj];
                float dr = avv[sj] * W1[i * 1024 + k] + d1v[sj] * acc[si][sj][r];
                pq += W1[(1024 + i) * 1024 + k] * dr;
                pp += W1[(2048 + i) * 1024 + k] * dr;
            }
            for (int o = 1; o < 16; o <<= 1) {
                pq += __shfl_xor(pq, o);
                pp += __shfl_xor(pp, o);
            }
            if (tx == 0) {
                atomicAdd(&out[i], pp);
                atomicAdd(&out[1024 + i], -pq);
            }
        }
    }
}

extern "C" void kernel_launch(void* const* d_in, const int* in_sizes, int n_in,
                              void* d_out, int out_size, void* d_ws, size_t ws_size,
                              hipStream_t stream) {
    const float* x = (const float*)d_in[0];
    const float* q = (const float*)d_in[1];
    const float* p = (const float*)d_in[2];
    const float* W1 = (const float*)d_in[3];
    const float* b1 = (const float*)d_in[4];
    const float* W2 = (const float*)d_in[5];
    const float* b2 = (const float*)d_in[6];
    const float* W3 = (const float*)d_in[7];
    float* out = (float*)d_out;
    float* ws = (float*)d_ws;
    float* H1 = ws, *D1 = ws + 1024, *Svec = ws + 2048, *Cvec = ws + 3072;
    float* Avec = ws + 4096, *Z = ws + 5120, *Uacc = ws + 8192;  // Vacc = Uacc+1024
    u16* u0 = (u16*)(ws + 16384);
    u16* Ah = u0;
    u16* Al = u0 + 1048576;
    u16* WTh = u0 + 2097152;
    u16* WTl = u0 + 3145728;
    u16* W2h = u0 + 4194304;
    u16* W2l = u0 + 5242880;
    u16* Sh = u0 + 6291456;
    u16* Sl = u0 + 7340032;

    k_init_prep<<<1036, 256, 0, stream>>>(x, q, p, W1, Z, out, Uacc, Ah, Al);
    k_u_partial<<<dim3(4, 48), 256, 0, stream>>>(W1, Z, Uacc);
    k_h1<<<4, 256, 0, stream>>>(Uacc, b1, H1, D1);
    k_w2v<<<dim3(16, 16), 256, 0, stream>>>(W2, D1, H1, W2h, W2l, WTh, WTl, Uacc + 1024);
    k_h2<<<4, 256, 0, stream>>>(Uacc + 1024, b2, W3, Svec, Cvec);
    k_g<<<1024, 256, 0, stream>>>(W2, Svec, H1, D1, Avec);
    k_gemm1<<<dim3(16, 16), 256, 0, stream>>>(Ah, Al, WTh, WTl, Cvec, Sh, Sl);
    k_gemm2<<<dim3(16, 16), 256, 0, stream>>>(Sh, Sl, W2h, W2l, W1, D1, Avec, out);
}

// Round 4
// 137.490 us; speedup vs baseline: 1.2150x; 1.2150x over previous
//
#include <hip/hip_runtime.h>
#include <math.h>

typedef unsigned short u16;
typedef __bf16 bf16x8 __attribute__((ext_vector_type(8)));
typedef float f32x4 __attribute__((ext_vector_type(4)));

// ---------- helpers ----------
__device__ inline u16 bf16_rn(float x) {
    unsigned u = __float_as_uint(x);
    return (u16)((u + 0x7FFFu + ((u >> 16) & 1u)) >> 16);
}
__device__ inline void split2(float x, u16& h, u16& l) {
    h = bf16_rn(x);
    float hf = __uint_as_float(((unsigned)h) << 16);
    l = bf16_rn(x - hf);
}
__device__ inline uint2 pack4(u16 a, u16 b, u16 c, u16 d) {
    uint2 r;
    r.x = (unsigned)a | ((unsigned)b << 16);
    r.y = (unsigned)c | ((unsigned)d << 16);
    return r;
}
__device__ inline f32x4 mfma16(bf16x8 a, bf16x8 b, f32x4 c) {
    return __builtin_amdgcn_mfma_f32_16x16x32_bf16(a, b, c, 0, 0, 0);
}

// ---------- small fp32 kernels (identical to the 144.8 us version) ----------
__global__ __launch_bounds__(256) void k_init(const float* __restrict__ x,
                                              const float* __restrict__ q,
                                              const float* __restrict__ p,
                                              float* __restrict__ Z,
                                              float* __restrict__ out,
                                              float* __restrict__ uv) {
    int j = blockIdx.x * 256 + threadIdx.x;  // grid 12 -> 3072
    if (j < 2048) { out[j] = 0.f; uv[j] = 0.f; }
    Z[j] = (j < 1024) ? x[j] : (j < 2048 ? q[j - 1024] : p[j - 2048]);
}

__global__ __launch_bounds__(256) void k_u_partial(const float* __restrict__ W1,
                                                   const float* __restrict__ Z,
                                                   float* __restrict__ Uacc) {
    int k = blockIdx.x * 256 + threadIdx.x;  // grid (4,48)
    int j0 = blockIdx.y * 64;
    __shared__ float zs[64];
    if (threadIdx.x < 64) zs[threadIdx.x] = Z[j0 + threadIdx.x];
    __syncthreads();
    float acc = 0.f;
#pragma unroll 8
    for (int j = 0; j < 64; ++j) acc += zs[j] * W1[(j0 + j) * 1024 + k];
    atomicAdd(&Uacc[k], acc);
}

__global__ __launch_bounds__(256) void k_h1(const float* __restrict__ Uacc,
                                            const float* __restrict__ b1,
                                            float* __restrict__ H1, float* __restrict__ D1) {
    int k = blockIdx.x * 256 + threadIdx.x;  // grid 4
    float h = tanhf(Uacc[k] + b1[k]);
    H1[k] = h;
    D1[k] = 1.f - h * h;
}

__global__ __launch_bounds__(256) void k_v_partial(const float* __restrict__ W2,
                                                   const float* __restrict__ H1,
                                                   float* __restrict__ Vacc) {
    int m = blockIdx.x * 256 + threadIdx.x;  // grid (4,16)
    int k0 = blockIdx.y * 64;
    __shared__ float hs[64];
    if (threadIdx.x < 64) hs[threadIdx.x] = H1[k0 + threadIdx.x];
    __syncthreads();
    float acc = 0.f;
#pragma unroll 8
    for (int k = 0; k < 64; ++k) acc += hs[k] * W2[(k0 + k) * 1024 + m];
    atomicAdd(&Vacc[m], acc);
}

__global__ __launch_bounds__(256) void k_h2(const float* __restrict__ Vacc,
                                            const float* __restrict__ b2,
                                            const float* __restrict__ W3,
                                            float* __restrict__ Svec, float* __restrict__ Cvec) {
    int m = blockIdx.x * 256 + threadIdx.x;  // grid 4
    float h = tanhf(Vacc[m] + b2[m]);
    float d2 = 1.f - h * h;
    float w3 = W3[m];
    Svec[m] = d2 * w3;
    Cvec[m] = -2.f * h * d2 * w3;
}

__global__ __launch_bounds__(256) void k_g(const float* __restrict__ W2,
                                           const float* __restrict__ Svec,
                                           const float* __restrict__ H1,
                                           const float* __restrict__ D1,
                                           float* __restrict__ Avec) {
    int k = blockIdx.x;  // grid 1024
    int t = threadIdx.x;
    float acc = 0.f;
#pragma unroll
    for (int m = t; m < 1024; m += 256) acc += W2[k * 1024 + m] * Svec[m];
    for (int o = 32; o; o >>= 1) acc += __shfl_down(acc, o);
    __shared__ float red[4];
    int lane = t & 63, w = t >> 6;
    if (lane == 0) red[w] = acc;
    __syncthreads();
    if (t == 0) Avec[k] = -2.f * H1[k] * D1[k] * (red[0] + red[1] + red[2] + red[3]);
}

// ---------- bf16 hi/lo prep ----------
__global__ __launch_bounds__(256) void k_prep_a(const float* __restrict__ W1,
                                                u16* __restrict__ Ah, u16* __restrict__ Al) {
    int idx = (blockIdx.x * 256 + threadIdx.x) * 4;  // grid 1024 -> 1M floats
    float4 v = *(const float4*)(W1 + idx);
    u16 h0, l0, h1, l1, h2, l2, h3, l3;
    split2(v.x, h0, l0); split2(v.y, h1, l1); split2(v.z, h2, l2); split2(v.w, h3, l3);
    *(uint2*)&Ah[idx] = pack4(h0, h1, h2, h3);
    *(uint2*)&Al[idx] = pack4(l0, l1, l2, l3);
}

__global__ __launch_bounds__(256) void k_prep_w2(const float* __restrict__ W2,
                                                 const float* __restrict__ D1,
                                                 u16* __restrict__ W2h, u16* __restrict__ W2l,
                                                 u16* __restrict__ WTh, u16* __restrict__ WTl) {
    __shared__ float T[64][65];
    int k0 = blockIdx.y * 64, m0 = blockIdx.x * 64;
    int t = threadIdx.x;
    int rr = t >> 4, cc = (t & 15) * 4;
#pragma unroll
    for (int j = 0; j < 4; ++j) {
        int r = rr + j * 16;
        float4 v = *(const float4*)(W2 + (k0 + r) * 1024 + m0 + cc);
        T[r][cc + 0] = v.x; T[r][cc + 1] = v.y; T[r][cc + 2] = v.z; T[r][cc + 3] = v.w;
        u16 h0, l0, h1, l1, h2, l2, h3, l3;
        split2(v.x, h0, l0); split2(v.y, h1, l1); split2(v.z, h2, l2); split2(v.w, h3, l3);
        *(uint2*)&W2h[(k0 + r) * 1024 + m0 + cc] = pack4(h0, h1, h2, h3);
        *(uint2*)&W2l[(k0 + r) * 1024 + m0 + cc] = pack4(l0, l1, l2, l3);
    }
    __syncthreads();
#pragma unroll
    for (int j = 0; j < 4; ++j) {
        int mrow = rr + j * 16;
        float f0 = T[cc + 0][mrow] * D1[k0 + cc + 0];
        float f1 = T[cc + 1][mrow] * D1[k0 + cc + 1];
        float f2 = T[cc + 2][mrow] * D1[k0 + cc + 2];
        float f3 = T[cc + 3][mrow] * D1[k0 + cc + 3];
        u16 h0, l0, h1, l1, h2, l2, h3, l3;
        split2(f0, h0, l0); split2(f1, h1, l1); split2(f2, h2, l2); split2(f3, h3, l3);
        *(uint2*)&WTh[(m0 + mrow) * 1024 + k0 + cc] = pack4(h0, h1, h2, h3);
        *(uint2*)&WTl[(m0 + mrow) * 1024 + k0 + cc] = pack4(l0, l1, l2, l3);
    }
}

// ---------- software-pipelined double-buffered MFMA GEMMs ----------
// LDS row stride 36 u16 (+4 pad): fragment-read bank starts r*18 mod 32 all
// distinct -> 2-way aliasing only (free). One barrier per K-step; global
// prefetch for step j+1 issues before the barrier of step j.
#define LDK 36
__global__ __launch_bounds__(256) void k_gemm1(const u16* __restrict__ Ah, const u16* __restrict__ Al,
                                               const u16* __restrict__ Bh, const u16* __restrict__ Bl,
                                               const float* __restrict__ Cvec,
                                               u16* __restrict__ Sh, u16* __restrict__ Sl) {
    __shared__ u16 As[2][2][64 * LDK];  // [buf][h/l]
    __shared__ u16 Bs[2][2][64 * LDK];
    int tid = threadIdx.x, lane = tid & 63, wv = tid >> 6;
    int wy = wv >> 1, wx = wv & 1;
    int i0 = blockIdx.y * 64, m0 = blockIdx.x * 64;
    int srow = tid >> 2, sseg = (tid & 3) * 8;
    int ldso = srow * LDK + sseg;
    const u16* ap_h = Ah + (i0 + srow) * 1024 + sseg;
    const u16* ap_l = Al + (i0 + srow) * 1024 + sseg;
    const u16* bp_h = Bh + (m0 + srow) * 1024 + sseg;
    const u16* bp_l = Bl + (m0 + srow) * 1024 + sseg;
    int tx = lane & 15, qy = lane >> 4;
    int ra0 = (wy * 32 + tx) * LDK + qy * 8;
    int ra1 = ra0 + 16 * LDK;
    int rb0 = (wx * 32 + tx) * LDK + qy * 8;
    int rb1 = rb0 + 16 * LDK;
    f32x4 acc[2][2];
#pragma unroll
    for (int a = 0; a < 2; ++a)
#pragma unroll
        for (int b = 0; b < 2; ++b) acc[a][b] = (f32x4){0.f, 0.f, 0.f, 0.f};

    // stage k0=0 into buf 0
    {
        uint4 va_h = *(const uint4*)(ap_h);
        uint4 va_l = *(const uint4*)(ap_l);
        uint4 vb_h = *(const uint4*)(bp_h);
        uint4 vb_l = *(const uint4*)(bp_l);
        *(uint4*)&As[0][0][ldso] = va_h;
        *(uint4*)&As[0][1][ldso] = va_l;
        *(uint4*)&Bs[0][0][ldso] = vb_h;
        *(uint4*)&Bs[0][1][ldso] = vb_l;
    }

    for (int k0 = 0; k0 < 1024; k0 += 32) {
        int buf = (k0 >> 5) & 1;
        int kn = (k0 + 32) & 1023;  // last iter wraps (staged but never read)
        uint4 na_h = *(const uint4*)(ap_h + kn);
        uint4 na_l = *(const uint4*)(ap_l + kn);
        uint4 nb_h = *(const uint4*)(bp_h + kn);
        uint4 nb_l = *(const uint4*)(bp_l + kn);
        __syncthreads();
        bf16x8 aH0 = *(const bf16x8*)&As[buf][0][ra0];
        bf16x8 aH1 = *(const bf16x8*)&As[buf][0][ra1];
        bf16x8 aL0 = *(const bf16x8*)&As[buf][1][ra0];
        bf16x8 aL1 = *(const bf16x8*)&As[buf][1][ra1];
        bf16x8 bH0 = *(const bf16x8*)&Bs[buf][0][rb0];
        bf16x8 bH1 = *(const bf16x8*)&Bs[buf][0][rb1];
        bf16x8 bL0 = *(const bf16x8*)&Bs[buf][1][rb0];
        bf16x8 bL1 = *(const bf16x8*)&Bs[buf][1][rb1];
        acc[0][0] = mfma16(aH0, bH0, acc[0][0]);
        acc[0][0] = mfma16(aH0, bL0, acc[0][0]);
        acc[0][0] = mfma16(aL0, bH0, acc[0][0]);
        acc[0][1] = mfma16(aH0, bH1, acc[0][1]);
        acc[0][1] = mfma16(aH0, bL1, acc[0][1]);
        acc[0][1] = mfma16(aL0, bH1, acc[0][1]);
        acc[1][0] = mfma16(aH1, bH0, acc[1][0]);
        acc[1][0] = mfma16(aH1, bL0, acc[1][0]);
        acc[1][0] = mfma16(aL1, bH0, acc[1][0]);
        acc[1][1] = mfma16(aH1, bH1, acc[1][1]);
        acc[1][1] = mfma16(aH1, bL1, acc[1][1]);
        acc[1][1] = mfma16(aL1, bH1, acc[1][1]);
        // stage next tile into the other buffer (vmcnt wait lands here,
        // one full iteration after issue)
        *(uint4*)&As[buf ^ 1][0][ldso] = na_h;
        *(uint4*)&As[buf ^ 1][1][ldso] = na_l;
        *(uint4*)&Bs[buf ^ 1][0][ldso] = nb_h;
        *(uint4*)&Bs[buf ^ 1][1][ldso] = nb_l;
    }
#pragma unroll
    for (int sj = 0; sj < 2; ++sj) {
        int m = m0 + wx * 32 + sj * 16 + tx;
        float cm = Cvec[m];
#pragma unroll
        for (int si = 0; si < 2; ++si) {
            int ib = i0 + wy * 32 + si * 16 + qy * 4;
#pragma unroll
            for (int r = 0; r < 4; ++r) {
                float v = acc[si][sj][r] * cm;
                u16 h, l;
                split2(v, h, l);
                Sh[(ib + r) * 1024 + m] = h;
                Sl[(ib + r) * 1024 + m] = l;
            }
        }
    }
}

__global__ __launch_bounds__(256) void k_gemm2(const u16* __restrict__ Sh, const u16* __restrict__ Sl,
                                               const u16* __restrict__ W2h, const u16* __restrict__ W2l,
                                               const float* __restrict__ W1,
                                               const float* __restrict__ D1,
                                               const float* __restrict__ Avec,
                                               float* __restrict__ out) {
    __shared__ u16 As[2][2][64 * LDK];
    __shared__ u16 Bs[2][2][64 * LDK];
    int tid = threadIdx.x, lane = tid & 63, wv = tid >> 6;
    int wy = wv >> 1, wx = wv & 1;
    int i0 = blockIdx.y * 64, k0g = blockIdx.x * 64;
    int srow = tid >> 2, sseg = (tid & 3) * 8;
    int ldso = srow * LDK + sseg;
    const u16* ap_h = Sh + (i0 + srow) * 1024 + sseg;
    const u16* ap_l = Sl + (i0 + srow) * 1024 + sseg;
    const u16* bp_h = W2h + (k0g + srow) * 1024 + sseg;
    const u16* bp_l = W2l + (k0g + srow) * 1024 + sseg;
    int tx = lane & 15, qy = lane >> 4;
    int ra0 = (wy * 32 + tx) * LDK + qy * 8;
    int ra1 = ra0 + 16 * LDK;
    int rb0 = (wx * 32 + tx) * LDK + qy * 8;
    int rb1 = rb0 + 16 * LDK;
    f32x4 acc[2][2];
#pragma unroll
    for (int a = 0; a < 2; ++a)
#pragma unroll
        for (int b = 0; b < 2; ++b) acc[a][b] = (f32x4){0.f, 0.f, 0.f, 0.f};

    {
        uint4 va_h = *(const uint4*)(ap_h);
        uint4 va_l = *(const uint4*)(ap_l);
        uint4 vb_h = *(const uint4*)(bp_h);
        uint4 vb_l = *(const uint4*)(bp_l);
        *(uint4*)&As[0][0][ldso] = va_h;
        *(uint4*)&As[0][1][ldso] = va_l;
        *(uint4*)&Bs[0][0][ldso] = vb_h;
        *(uint4*)&Bs[0][1][ldso] = vb_l;
    }

    for (int m0 = 0; m0 < 1024; m0 += 32) {
        int buf = (m0 >> 5) & 1;
        int mn = (m0 + 32) & 1023;
        uint4 na_h = *(const uint4*)(ap_h + mn);
        uint4 na_l = *(const uint4*)(ap_l + mn);
        uint4 nb_h = *(const uint4*)(bp_h + mn);
        uint4 nb_l = *(const uint4*)(bp_l + mn);
        __syncthreads();
        bf16x8 aH0 = *(const bf16x8*)&As[buf][0][ra0];
        bf16x8 aH1 = *(const bf16x8*)&As[buf][0][ra1];
        bf16x8 aL0 = *(const bf16x8*)&As[buf][1][ra0];
        bf16x8 aL1 = *(const bf16x8*)&As[buf][1][ra1];
        bf16x8 bH0 = *(const bf16x8*)&Bs[buf][0][rb0];
        bf16x8 bH1 = *(const bf16x8*)&Bs[buf][0][rb1];
        bf16x8 bL0 = *(const bf16x8*)&Bs[buf][1][rb0];
        bf16x8 bL1 = *(const bf16x8*)&Bs[buf][1][rb1];
        acc[0][0] = mfma16(aH0, bH0, acc[0][0]);
        acc[0][0] = mfma16(aH0, bL0, acc[0][0]);
        acc[0][0] = mfma16(aL0, bH0, acc[0][0]);
        acc[0][1] = mfma16(aH0, bH1, acc[0][1]);
        acc[0][1] = mfma16(aH0, bL1, acc[0][1]);
        acc[0][1] = mfma16(aL0, bH1, acc[0][1]);
        acc[1][0] = mfma16(aH1, bH0, acc[1][0]);
        acc[1][0] = mfma16(aH1, bL0, acc[1][0]);
        acc[1][0] = mfma16(aL1, bH0, acc[1][0]);
        acc[1][1] = mfma16(aH1, bH1, acc[1][1]);
        acc[1][1] = mfma16(aH1, bL1, acc[1][1]);
        acc[1][1] = mfma16(aL1, bH1, acc[1][1]);
        *(uint4*)&As[buf ^ 1][0][ldso] = na_h;
        *(uint4*)&As[buf ^ 1][1][ldso] = na_l;
        *(uint4*)&Bs[buf ^ 1][0][ldso] = nb_h;
        *(uint4*)&Bs[buf ^ 1][1][ldso] = nb_l;
    }
    // fused epilogue: DR = Avec[k]*W1[i,k] + D1[k]*Wm[i,k]; dot with q/p rows of W1
    int kk[2];
    float d1v[2], avv[2];
#pragma unroll
    for (int sj = 0; sj < 2; ++sj) {
        kk[sj] = k0g + wx * 32 + sj * 16 + tx;
        d1v[sj] = D1[kk[sj]];
        avv[sj] = Avec[kk[sj]];
    }
#pragma unroll
    for (int si = 0; si < 2; ++si) {
        int ib = i0 + wy * 32 + si * 16 + qy * 4;
#pragma unroll
        for (int r = 0; r < 4; ++r) {
            int i = ib + r;
            float pq = 0.f, pp = 0.f;
#pragma unroll
            for (int sj = 0; sj < 2; ++sj) {
                int k = kk[sj];
                float dr = avv[sj] * W1[i * 1024 + k] + d1v[sj] * acc[si][sj][r];
                pq += W1[(1024 + i) * 1024 + k] * dr;
                pp += W1[(2048 + i) * 1024 + k] * dr;
            }
            for (int o = 1; o < 16; o <<= 1) {
                pq += __shfl_xor(pq, o);
                pp += __shfl_xor(pp, o);
            }
            if (tx == 0) {
                atomicAdd(&out[i], pp);
                atomicAdd(&out[1024 + i], -pq);
            }
        }
    }
}

extern "C" void kernel_launch(void* const* d_in, const int* in_sizes, int n_in,
                              void* d_out, int out_size, void* d_ws, size_t ws_size,
                              hipStream_t stream) {
    const float* x = (const float*)d_in[0];
    const float* q = (const float*)d_in[1];
    const float* p = (const float*)d_in[2];
    const float* W1 = (const float*)d_in[3];
    const float* b1 = (const float*)d_in[4];
    const float* W2 = (const float*)d_in[5];
    const float* b2 = (const float*)d_in[6];
    const float* W3 = (const float*)d_in[7];
    float* out = (float*)d_out;
    float* ws = (float*)d_ws;
    float* H1 = ws, *D1 = ws + 1024, *Svec = ws + 2048, *Cvec = ws + 3072;
    float* Avec = ws + 4096, *Z = ws + 5120, *Uacc = ws + 8192;  // Vacc = Uacc+1024
    u16* u0 = (u16*)(ws + 16384);
    u16* Ah = u0;
    u16* Al = u0 + 1048576;
    u16* WTh = u0 + 2097152;
    u16* WTl = u0 + 3145728;
    u16* W2h = u0 + 4194304;
    u16* W2l = u0 + 5242880;
    u16* Sh = u0 + 6291456;
    u16* Sl = u0 + 7340032;

    k_init<<<12, 256, 0, stream>>>(x, q, p, Z, out, Uacc);
    k_prep_a<<<1024, 256, 0, stream>>>(W1, Ah, Al);
    k_u_partial<<<dim3(4, 48), 256, 0, stream>>>(W1, Z, Uacc);
    k_h1<<<4, 256, 0, stream>>>(Uacc, b1, H1, D1);
    k_prep_w2<<<dim3(16, 16), 256, 0, stream>>>(W2, D1, W2h, W2l, WTh, WTl);
    k_v_partial<<<dim3(4, 16), 256, 0, stream>>>(W2, H1, Uacc + 1024);
    k_h2<<<4, 256, 0, stream>>>(Uacc + 1024, b2, W3, Svec, Cvec);
    k_g<<<1024, 256, 0, stream>>>(W2, Svec, H1, D1, Avec);
    k_gemm1<<<dim3(16, 16), 256, 0, stream>>>(Ah, Al, WTh, WTl, Cvec, Sh, Sl);
    k_gemm2<<<dim3(16, 16), 256, 0, stream>>>(Sh, Sl, W2h, W2l, W1, D1, Avec, out);
}

// Round 5
// 131.541 us; speedup vs baseline: 1.2699x; 1.0452x over previous
//
#include <hip/hip_runtime.h>
#include <math.h>

typedef unsigned short u16;
typedef __bf16 bf16x8 __attribute__((ext_vector_type(8)));
typedef float f32x4 __attribute__((ext_vector_type(4)));

// ---------- helpers ----------
__device__ inline u16 bf16_rn(float x) {
    unsigned u = __float_as_uint(x);
    return (u16)((u + 0x7FFFu + ((u >> 16) & 1u)) >> 16);
}
__device__ inline void split2(float x, u16& h, u16& l) {
    h = bf16_rn(x);
    float hf = __uint_as_float(((unsigned)h) << 16);
    l = bf16_rn(x - hf);
}
__device__ inline uint2 pack4(u16 a, u16 b, u16 c, u16 d) {
    uint2 r;
    r.x = (unsigned)a | ((unsigned)b << 16);
    r.y = (unsigned)c | ((unsigned)d << 16);
    return r;
}
__device__ inline f32x4 mfma16(bf16x8 a, bf16x8 b, f32x4 c) {
    return __builtin_amdgcn_mfma_f32_16x16x32_bf16(a, b, c, 0, 0, 0);
}

// ---------- Node A: prep_a (b<1024) + u-partials (1024..1215) + zero (1216..1218) ----------
__global__ __launch_bounds__(256) void k_pre(const float* __restrict__ x,
                                             const float* __restrict__ q,
                                             const float* __restrict__ p,
                                             const float* __restrict__ W1,
                                             u16* __restrict__ Ah, u16* __restrict__ Al,
                                             float* __restrict__ Upart,
                                             float* __restrict__ out,
                                             float* __restrict__ Vacc) {
    int b = blockIdx.x, t = threadIdx.x;
    if (b < 1024) {
        int idx = (b * 256 + t) * 4;  // W1 rows 0..1023 (A block)
        float4 v = *(const float4*)(W1 + idx);
        u16 h0, l0, h1, l1, h2, l2, h3, l3;
        split2(v.x, h0, l0); split2(v.y, h1, l1); split2(v.z, h2, l2); split2(v.w, h3, l3);
        *(uint2*)&Ah[idx] = pack4(h0, h1, h2, h3);
        *(uint2*)&Al[idx] = pack4(l0, l1, l2, l3);
    } else if (b < 1216) {
        int jc = b - 1024;             // 0..191
        int k = (jc & 3) * 256 + t;    // 4 k-groups
        int j0 = (jc >> 2) * 64;       // 48 j-chunks (64-aligned, never straddles x/q/p)
        __shared__ float zs[64];
        if (t < 64) {
            int j = j0 + t;
            zs[t] = (j < 1024) ? x[j] : (j < 2048 ? q[j - 1024] : p[j - 2048]);
        }
        __syncthreads();
        float acc = 0.f;
#pragma unroll 8
        for (int j = 0; j < 64; ++j) acc += zs[j] * W1[(j0 + j) * 1024 + k];
        Upart[(jc >> 2) * 1024 + k] = acc;  // plain store, no atomics
    } else {
        int idx = ((b - 1216) * 256 + t) * 4;  // 3072 floats: out[2048] + Vacc[1024]
        if (idx < 2048) *(float4*)(out + idx) = make_float4(0.f, 0.f, 0.f, 0.f);
        else *(float4*)(Vacc + idx - 2048) = make_float4(0.f, 0.f, 0.f, 0.f);
    }
}

// ---------- Node C: reduce U -> h1/d1 (local), split W2 -> W2h/W2l, transpose+d1-scale
// -> WTh/WTl, Vacc partials; m0==0 blocks publish H1/D1 ----------
__global__ __launch_bounds__(256) void k_w2v(const float* __restrict__ W2,
                                             const float* __restrict__ b1,
                                             const float* __restrict__ Upart,
                                             float* __restrict__ H1g, float* __restrict__ D1g,
                                             u16* __restrict__ W2h, u16* __restrict__ W2l,
                                             u16* __restrict__ WTh, u16* __restrict__ WTl,
                                             float* __restrict__ Vacc) {
    __shared__ float T[64][65];
    __shared__ float hs[64], ds[64];
    int k0 = blockIdx.y * 64, m0 = blockIdx.x * 64;
    int t = threadIdx.x;
    if (t < 64) {
        float u = 0.f;
#pragma unroll 8
        for (int c = 0; c < 48; ++c) u += Upart[c * 1024 + k0 + t];
        float h = tanhf(u + b1[k0 + t]);
        hs[t] = h;
        ds[t] = 1.f - h * h;
        if (m0 == 0) { H1g[k0 + t] = h; D1g[k0 + t] = 1.f - h * h; }
    }
    __syncthreads();
    int rr = t >> 4, cc = (t & 15) * 4;
    float4 vp = make_float4(0.f, 0.f, 0.f, 0.f);
#pragma unroll
    for (int j = 0; j < 4; ++j) {
        int r = rr + j * 16;
        float4 v = *(const float4*)(W2 + (k0 + r) * 1024 + m0 + cc);
        T[r][cc + 0] = v.x; T[r][cc + 1] = v.y; T[r][cc + 2] = v.z; T[r][cc + 3] = v.w;
        u16 h0, l0, h1, l1, h2, l2, h3, l3;
        split2(v.x, h0, l0); split2(v.y, h1, l1); split2(v.z, h2, l2); split2(v.w, h3, l3);
        *(uint2*)&W2h[(k0 + r) * 1024 + m0 + cc] = pack4(h0, h1, h2, h3);
        *(uint2*)&W2l[(k0 + r) * 1024 + m0 + cc] = pack4(l0, l1, l2, l3);
        float hk = hs[r];
        vp.x += hk * v.x; vp.y += hk * v.y; vp.z += hk * v.z; vp.w += hk * v.w;
    }
    vp.x += __shfl_xor(vp.x, 16); vp.y += __shfl_xor(vp.y, 16);
    vp.z += __shfl_xor(vp.z, 16); vp.w += __shfl_xor(vp.w, 16);
    vp.x += __shfl_xor(vp.x, 32); vp.y += __shfl_xor(vp.y, 32);
    vp.z += __shfl_xor(vp.z, 32); vp.w += __shfl_xor(vp.w, 32);
    if (((t & 63) >> 4) == 0) {
        atomicAdd(&Vacc[m0 + cc + 0], vp.x);
        atomicAdd(&Vacc[m0 + cc + 1], vp.y);
        atomicAdd(&Vacc[m0 + cc + 2], vp.z);
        atomicAdd(&Vacc[m0 + cc + 3], vp.w);
    }
    __syncthreads();
#pragma unroll
    for (int j = 0; j < 4; ++j) {
        int mrow = rr + j * 16;
        float f0 = T[cc + 0][mrow] * ds[cc + 0];
        float f1 = T[cc + 1][mrow] * ds[cc + 1];
        float f2 = T[cc + 2][mrow] * ds[cc + 2];
        float f3 = T[cc + 3][mrow] * ds[cc + 3];
        u16 h0, l0, h1, l1, h2, l2, h3, l3;
        split2(f0, h0, l0); split2(f1, h1, l1); split2(f2, h2, l2); split2(f3, h3, l3);
        *(uint2*)&WTh[(m0 + mrow) * 1024 + k0 + cc] = pack4(h0, h1, h2, h3);
        *(uint2*)&WTl[(m0 + mrow) * 1024 + k0 + cc] = pack4(l0, l1, l2, l3);
    }
}

// ---------- Node k_g: Avec[k] = -2 h1 d1 * (W2[k,:] . Svec), Svec built in LDS from Vacc ----------
__global__ __launch_bounds__(256) void k_g(const float* __restrict__ W2,
                                           const float* __restrict__ Vacc,
                                           const float* __restrict__ b2,
                                           const float* __restrict__ W3,
                                           const float* __restrict__ H1,
                                           const float* __restrict__ D1,
                                           float* __restrict__ Avec) {
    __shared__ float sv[1024];
    int k = blockIdx.x;  // grid 1024
    int t = threadIdx.x;
#pragma unroll
    for (int j = 0; j < 4; ++j) {
        int m = t * 4 + j;
        float h = tanhf(Vacc[m] + b2[m]);
        sv[m] = (1.f - h * h) * W3[m];
    }
    __syncthreads();
    float acc = 0.f;
#pragma unroll
    for (int m = t; m < 1024; m += 256) acc += W2[k * 1024 + m] * sv[m];
    for (int o = 32; o; o >>= 1) acc += __shfl_down(acc, o);
    __shared__ float red[4];
    int lane = t & 63, w = t >> 6;
    if (lane == 0) red[w] = acc;
    __syncthreads();
    if (t == 0) Avec[k] = -2.f * H1[k] * D1[k] * (red[0] + red[1] + red[2] + red[3]);
}

// ---------- dbuf BK=64 MFMA GEMMs (single barrier/iter, verified core) ----------
#define LDK 68
__global__ __launch_bounds__(256) void k_gemm1(const u16* __restrict__ Ah, const u16* __restrict__ Al,
                                               const u16* __restrict__ Bh, const u16* __restrict__ Bl,
                                               const float* __restrict__ Vacc,
                                               const float* __restrict__ b2,
                                               const float* __restrict__ W3,
                                               u16* __restrict__ Sh, u16* __restrict__ Sl) {
    __shared__ u16 As[2][2][64 * LDK];  // [buf][h/l]
    __shared__ u16 Bs[2][2][64 * LDK];
    int tid = threadIdx.x, lane = tid & 63, wv = tid >> 6;
    int wy = wv >> 1, wx = wv & 1;
    int i0 = blockIdx.y * 64, m0 = blockIdx.x * 64;
    int srow = tid >> 2, sseg = (tid & 3) * 16;
    int ldso = srow * LDK + sseg;
    const u16* ap_h = Ah + (i0 + srow) * 1024 + sseg;
    const u16* ap_l = Al + (i0 + srow) * 1024 + sseg;
    const u16* bp_h = Bh + (m0 + srow) * 1024 + sseg;
    const u16* bp_l = Bl + (m0 + srow) * 1024 + sseg;
    int tx = lane & 15, qy = lane >> 4;
    int raA0 = (wy * 32 + tx) * LDK, raA1 = raA0 + 16 * LDK;
    int rbB0 = (wx * 32 + tx) * LDK, rbB1 = rbB0 + 16 * LDK;
    f32x4 acc[2][2];
#pragma unroll
    for (int a = 0; a < 2; ++a)
#pragma unroll
        for (int b = 0; b < 2; ++b) acc[a][b] = (f32x4){0.f, 0.f, 0.f, 0.f};

    // stage k0=0 into buf 0
    *(uint4*)&As[0][0][ldso] = *(const uint4*)(ap_h);
    *(uint4*)&As[0][0][ldso + 8] = *(const uint4*)(ap_h + 8);
    *(uint4*)&As[0][1][ldso] = *(const uint4*)(ap_l);
    *(uint4*)&As[0][1][ldso + 8] = *(const uint4*)(ap_l + 8);
    *(uint4*)&Bs[0][0][ldso] = *(const uint4*)(bp_h);
    *(uint4*)&Bs[0][0][ldso + 8] = *(const uint4*)(bp_h + 8);
    *(uint4*)&Bs[0][1][ldso] = *(const uint4*)(bp_l);
    *(uint4*)&Bs[0][1][ldso + 8] = *(const uint4*)(bp_l + 8);

    for (int k0 = 0; k0 < 1024; k0 += 64) {
        int buf = (k0 >> 6) & 1;
        int kn = (k0 + 64) & 1023;  // last iter wraps (staged but never read)
        uint4 pa0 = *(const uint4*)(ap_h + kn), pa1 = *(const uint4*)(ap_h + kn + 8);
        uint4 pb0 = *(const uint4*)(ap_l + kn), pb1 = *(const uint4*)(ap_l + kn + 8);
        uint4 pc0 = *(const uint4*)(bp_h + kn), pc1 = *(const uint4*)(bp_h + kn + 8);
        uint4 pd0 = *(const uint4*)(bp_l + kn), pd1 = *(const uint4*)(bp_l + kn + 8);
        __syncthreads();
#pragma unroll
        for (int ks = 0; ks < 2; ++ks) {
            int o = ks * 32 + qy * 8;
            bf16x8 aH0 = *(const bf16x8*)&As[buf][0][raA0 + o];
            bf16x8 aH1 = *(const bf16x8*)&As[buf][0][raA1 + o];
            bf16x8 aL0 = *(const bf16x8*)&As[buf][1][raA0 + o];
            bf16x8 aL1 = *(const bf16x8*)&As[buf][1][raA1 + o];
            bf16x8 bH0 = *(const bf16x8*)&Bs[buf][0][rbB0 + o];
            bf16x8 bH1 = *(const bf16x8*)&Bs[buf][0][rbB1 + o];
            bf16x8 bL0 = *(const bf16x8*)&Bs[buf][1][rbB0 + o];
            bf16x8 bL1 = *(const bf16x8*)&Bs[buf][1][rbB1 + o];
            acc[0][0] = mfma16(aH0, bH0, acc[0][0]);
            acc[0][0] = mfma16(aH0, bL0, acc[0][0]);
            acc[0][0] = mfma16(aL0, bH0, acc[0][0]);
            acc[0][1] = mfma16(aH0, bH1, acc[0][1]);
            acc[0][1] = mfma16(aH0, bL1, acc[0][1]);
            acc[0][1] = mfma16(aL0, bH1, acc[0][1]);
            acc[1][0] = mfma16(aH1, bH0, acc[1][0]);
            acc[1][0] = mfma16(aH1, bL0, acc[1][0]);
            acc[1][0] = mfma16(aL1, bH0, acc[1][0]);
            acc[1][1] = mfma16(aH1, bH1, acc[1][1]);
            acc[1][1] = mfma16(aH1, bL1, acc[1][1]);
            acc[1][1] = mfma16(aL1, bH1, acc[1][1]);
        }
        int nb = buf ^ 1;
        *(uint4*)&As[nb][0][ldso] = pa0; *(uint4*)&As[nb][0][ldso + 8] = pa1;
        *(uint4*)&As[nb][1][ldso] = pb0; *(uint4*)&As[nb][1][ldso + 8] = pb1;
        *(uint4*)&Bs[nb][0][ldso] = pc0; *(uint4*)&Bs[nb][0][ldso + 8] = pc1;
        *(uint4*)&Bs[nb][1][ldso] = pd0; *(uint4*)&Bs[nb][1][ldso + 8] = pd1;
    }
#pragma unroll
    for (int sj = 0; sj < 2; ++sj) {
        int m = m0 + wx * 32 + sj * 16 + tx;
        float hv = tanhf(Vacc[m] + b2[m]);
        float d2 = 1.f - hv * hv;
        float cm = -2.f * hv * d2 * W3[m];  // Cvec inline
#pragma unroll
        for (int si = 0; si < 2; ++si) {
            int ib = i0 + wy * 32 + si * 16 + qy * 4;
#pragma unroll
            for (int r = 0; r < 4; ++r) {
                float v = acc[si][sj][r] * cm;
                u16 h, l;
                split2(v, h, l);
                Sh[(ib + r) * 1024 + m] = h;
                Sl[(ib + r) * 1024 + m] = l;
            }
        }
    }
}

__global__ __launch_bounds__(256) void k_gemm2(const u16* __restrict__ Sh, const u16* __restrict__ Sl,
                                               const u16* __restrict__ W2h, const u16* __restrict__ W2l,
                                               const float* __restrict__ W1,
                                               const float* __restrict__ D1,
                                               const float* __restrict__ Avec,
                                               float* __restrict__ out) {
    __shared__ u16 As[2][2][64 * LDK];
    __shared__ u16 Bs[2][2][64 * LDK];
    int tid = threadIdx.x, lane = tid & 63, wv = tid >> 6;
    int wy = wv >> 1, wx = wv & 1;
    int i0 = blockIdx.y * 64, k0g = blockIdx.x * 64;
    int srow = tid >> 2, sseg = (tid & 3) * 16;
    int ldso = srow * LDK + sseg;
    const u16* ap_h = Sh + (i0 + srow) * 1024 + sseg;
    const u16* ap_l = Sl + (i0 + srow) * 1024 + sseg;
    const u16* bp_h = W2h + (k0g + srow) * 1024 + sseg;
    const u16* bp_l = W2l + (k0g + srow) * 1024 + sseg;
    int tx = lane & 15, qy = lane >> 4;
    int raA0 = (wy * 32 + tx) * LDK, raA1 = raA0 + 16 * LDK;
    int rbB0 = (wx * 32 + tx) * LDK, rbB1 = rbB0 + 16 * LDK;
    f32x4 acc[2][2];
#pragma unroll
    for (int a = 0; a < 2; ++a)
#pragma unroll
        for (int b = 0; b < 2; ++b) acc[a][b] = (f32x4){0.f, 0.f, 0.f, 0.f};

    *(uint4*)&As[0][0][ldso] = *(const uint4*)(ap_h);
    *(uint4*)&As[0][0][ldso + 8] = *(const uint4*)(ap_h + 8);
    *(uint4*)&As[0][1][ldso] = *(const uint4*)(ap_l);
    *(uint4*)&As[0][1][ldso + 8] = *(const uint4*)(ap_l + 8);
    *(uint4*)&Bs[0][0][ldso] = *(const uint4*)(bp_h);
    *(uint4*)&Bs[0][0][ldso + 8] = *(const uint4*)(bp_h + 8);
    *(uint4*)&Bs[0][1][ldso] = *(const uint4*)(bp_l);
    *(uint4*)&Bs[0][1][ldso + 8] = *(const uint4*)(bp_l + 8);

    for (int m0 = 0; m0 < 1024; m0 += 64) {
        int buf = (m0 >> 6) & 1;
        int mn = (m0 + 64) & 1023;
        uint4 pa0 = *(const uint4*)(ap_h + mn), pa1 = *(const uint4*)(ap_h + mn + 8);
        uint4 pb0 = *(const uint4*)(ap_l + mn), pb1 = *(const uint4*)(ap_l + mn + 8);
        uint4 pc0 = *(const uint4*)(bp_h + mn), pc1 = *(const uint4*)(bp_h + mn + 8);
        uint4 pd0 = *(const uint4*)(bp_l + mn), pd1 = *(const uint4*)(bp_l + mn + 8);
        __syncthreads();
#pragma unroll
        for (int ks = 0; ks < 2; ++ks) {
            int o = ks * 32 + qy * 8;
            bf16x8 aH0 = *(const bf16x8*)&As[buf][0][raA0 + o];
            bf16x8 aH1 = *(const bf16x8*)&As[buf][0][raA1 + o];
            bf16x8 aL0 = *(const bf16x8*)&As[buf][1][raA0 + o];
            bf16x8 aL1 = *(const bf16x8*)&As[buf][1][raA1 + o];
            bf16x8 bH0 = *(const bf16x8*)&Bs[buf][0][rbB0 + o];
            bf16x8 bH1 = *(const bf16x8*)&Bs[buf][0][rbB1 + o];
            bf16x8 bL0 = *(const bf16x8*)&Bs[buf][1][rbB0 + o];
            bf16x8 bL1 = *(const bf16x8*)&Bs[buf][1][rbB1 + o];
            acc[0][0] = mfma16(aH0, bH0, acc[0][0]);
            acc[0][0] = mfma16(aH0, bL0, acc[0][0]);
            acc[0][0] = mfma16(aL0, bH0, acc[0][0]);
            acc[0][1] = mfma16(aH0, bH1, acc[0][1]);
            acc[0][1] = mfma16(aH0, bL1, acc[0][1]);
            acc[0][1] = mfma16(aL0, bH1, acc[0][1]);
            acc[1][0] = mfma16(aH1, bH0, acc[1][0]);
            acc[1][0] = mfma16(aH1, bL0, acc[1][0]);
            acc[1][0] = mfma16(aL1, bH0, acc[1][0]);
            acc[1][1] = mfma16(aH1, bH1, acc[1][1]);
            acc[1][1] = mfma16(aH1, bL1, acc[1][1]);
            acc[1][1] = mfma16(aL1, bH1, acc[1][1]);
        }
        int nb = buf ^ 1;
        *(uint4*)&As[nb][0][ldso] = pa0; *(uint4*)&As[nb][0][ldso + 8] = pa1;
        *(uint4*)&As[nb][1][ldso] = pb0; *(uint4*)&As[nb][1][ldso + 8] = pb1;
        *(uint4*)&Bs[nb][0][ldso] = pc0; *(uint4*)&Bs[nb][0][ldso + 8] = pc1;
        *(uint4*)&Bs[nb][1][ldso] = pd0; *(uint4*)&Bs[nb][1][ldso + 8] = pd1;
    }
    // fused epilogue: DR = Avec[k]*W1[i,k] + D1[k]*Wm[i,k]; dot with q/p rows of W1
    int kk[2];
    float d1v[2], avv[2];
#pragma unroll
    for (int sj = 0; sj < 2; ++sj) {
        kk[sj] = k0g + wx * 32 + sj * 16 + tx;
        d1v[sj] = D1[kk[sj]];
        avv[sj] = Avec[kk[sj]];
    }
#pragma unroll
    for (int si = 0; si < 2; ++si) {
        int ib = i0 + wy * 32 + si * 16 + qy * 4;
#pragma unroll
        for (int r = 0; r < 4; ++r) {
            int i = ib + r;
            float pq = 0.f, pp = 0.f;
#pragma unroll
            for (int sj = 0; sj < 2; ++sj) {
                int k = kk[sj];
                float dr = avv[sj] * W1[i * 1024 + k] + d1v[sj] * acc[si][sj][r];
                pq += W1[(1024 + i) * 1024 + k] * dr;
                pp += W1[(2048 + i) * 1024 + k] * dr;
            }
            for (int o = 1; o < 16; o <<= 1) {
                pq += __shfl_xor(pq, o);
                pp += __shfl_xor(pp, o);
            }
            if (tx == 0) {
                atomicAdd(&out[i], pp);
                atomicAdd(&out[1024 + i], -pq);
            }
        }
    }
}

extern "C" void kernel_launch(void* const* d_in, const int* in_sizes, int n_in,
                              void* d_out, int out_size, void* d_ws, size_t ws_size,
                              hipStream_t stream) {
    const float* x = (const float*)d_in[0];
    const float* q = (const float*)d_in[1];
    const float* p = (const float*)d_in[2];
    const float* W1 = (const float*)d_in[3];
    const float* b1 = (const float*)d_in[4];
    const float* W2 = (const float*)d_in[5];
    const float* b2 = (const float*)d_in[6];
    const float* W3 = (const float*)d_in[7];
    float* out = (float*)d_out;
    float* ws = (float*)d_ws;
    float* H1 = ws, *D1 = ws + 1024, *Avec = ws + 2048, *Vacc = ws + 3072;
    float* Upart = ws + 4096;  // 48*1024 floats
    u16* u0 = (u16*)(ws + 65536);
    u16* Ah = u0;
    u16* Al = u0 + 1048576;
    u16* WTh = u0 + 2097152;
    u16* WTl = u0 + 3145728;
    u16* W2h = u0 + 4194304;
    u16* W2l = u0 + 5242880;
    u16* Sh = u0 + 6291456;
    u16* Sl = u0 + 7340032;

    k_pre<<<1219, 256, 0, stream>>>(x, q, p, W1, Ah, Al, Upart, out, Vacc);
    k_w2v<<<dim3(16, 16), 256, 0, stream>>>(W2, b1, Upart, H1, D1, W2h, W2l, WTh, WTl, Vacc);
    k_gemm1<<<dim3(16, 16), 256, 0, stream>>>(Ah, Al, WTh, WTl, Vacc, b2, W3, Sh, Sl);
    k_g<<<1024, 256, 0, stream>>>(W2, Vacc, b2, W3, H1, D1, Avec);
    k_gemm2<<<dim3(16, 16), 256, 0, stream>>>(Sh, Sl, W2h, W2l, W1, D1, Avec, out);
}